// Round 1
// baseline (3466.048 us; speedup 1.0000x reference)
//
#include <hip/hip_runtime.h>
#include <hip/hip_bf16.h>

#define N_NODES 100000
#define N_EDGES 1600000
#define E_SL (N_EDGES + N_NODES)
#define HID 64
#define NUM_GRAPHS 64
#define NEG_SLOPE 0.2f

// float atomic max via sign-split: positives ordered as int, negatives reverse-ordered as uint.
// Works with memory initialized to 0xFFFFFFFF (int -1 / uint max).
__device__ __forceinline__ void atomicMaxFloat(float* addr, float v) {
    if (v >= 0.0f) atomicMax((int*)addr, __float_as_int(v));
    else           atomicMin((unsigned int*)addr, __float_as_uint(v));
}

// ---- self-loop attr: in-degree count + edge_attr segment-sum (8 threads/edge) ----
__global__ void deg_sum_kernel(const int* __restrict__ ei, const float* __restrict__ ea,
                               float* __restrict__ cnt, float* __restrict__ msum) {
    long long idx = (long long)blockIdx.x * blockDim.x + threadIdx.x;
    if (idx >= (long long)N_EDGES * 8) return;
    int e = (int)(idx >> 3), j = (int)(idx & 7);
    int d = ei[N_EDGES + e];
    atomicAdd(&msum[(size_t)d * 8 + j], ea[idx]);
    if (j == 0) atomicAdd(&cnt[d], 1.0f);
}

__global__ void mean_fin_kernel(const float* __restrict__ cnt, float* __restrict__ msum) {
    int i = blockIdx.x * blockDim.x + threadIdx.x;
    if (i >= N_NODES * 8) return;
    float c = fmaxf(cnt[i >> 3], 1.0f);
    msum[i] /= c;
}

// ---- fold We (8x64) and att_e (4x16) into we_eff[8][4] ----
__global__ void weff_kernel(const float* __restrict__ We, const float* __restrict__ ae,
                            float* __restrict__ weff) {
    int t = threadIdx.x;
    if (t >= 32) return;
    int dd = t >> 2, h = t & 3;
    float s = 0.f;
    #pragma unroll
    for (int c = 0; c < 16; ++c) s += We[dd * 64 + h * 16 + c] * ae[h * 16 + c];
    weff[dd * 4 + h] = s;
}

// ---- xp = x @ W ; al_s/al_d per-node logits. One wave per node (64 cols). ----
template <int FIN>
__global__ void xp_kernel(const float* __restrict__ xin, const float* __restrict__ W,
                          const float* __restrict__ a_s, const float* __restrict__ a_d,
                          float* __restrict__ xp, float* __restrict__ als, float* __restrict__ ald) {
    __shared__ float Wl[FIN * 64];
    __shared__ float xr[4 * FIN];
    int tid = threadIdx.x;
    for (int i = tid; i < FIN * 64; i += 256) Wl[i] = W[i];
    int n0 = blockIdx.x * 4;
    for (int i = tid; i < 4 * FIN; i += 256) {
        int r = i / FIN, k = i - r * FIN;
        int n = n0 + r;
        xr[i] = (n < N_NODES) ? xin[(size_t)n * FIN + k] : 0.f;
    }
    __syncthreads();
    int w = tid >> 6, lane = tid & 63;
    int n = n0 + w;
    if (n >= N_NODES) return;
    float acc = 0.f;
    const float* xrow = xr + w * FIN;
    #pragma unroll
    for (int k = 0; k < FIN; ++k) acc += xrow[k] * Wl[k * 64 + lane];
    xp[(size_t)n * 64 + lane] = acc;
    float ps = acc * a_s[lane];
    float pd = acc * a_d[lane];
    #pragma unroll
    for (int mk = 8; mk >= 1; mk >>= 1) {
        ps += __shfl_xor(ps, mk, 16);
        pd += __shfl_xor(pd, mk, 16);
    }
    if ((lane & 15) == 0) {
        als[(size_t)n * 4 + (lane >> 4)] = ps;
        ald[(size_t)n * 4 + (lane >> 4)] = pd;
    }
}

// ---- pass A: alpha = leaky_relu(al_s[src]+al_d[dst]+ea.we_eff); atomic segment max ----
__global__ void attn_logit_kernel(const int* __restrict__ ei,
                                  const float* __restrict__ ea, const float* __restrict__ mattr,
                                  const float* __restrict__ als, const float* __restrict__ ald,
                                  const float* __restrict__ weff,
                                  float* __restrict__ alpha, float* __restrict__ m) {
    int e = blockIdx.x * blockDim.x + threadIdx.x;
    if (e >= E_SL) return;
    int s, d; const float* ap;
    if (e < N_EDGES) { s = ei[e]; d = ei[N_EDGES + e]; ap = ea + (size_t)e * 8; }
    else             { s = e - N_EDGES; d = s;          ap = mattr + (size_t)s * 8; }
    float4 a0 = *(const float4*)ap;
    float4 a1 = *(const float4*)(ap + 4);
    float av[8] = {a0.x, a0.y, a0.z, a0.w, a1.x, a1.y, a1.z, a1.w};
    float4 as4 = *(const float4*)(als + (size_t)s * 4);
    float4 ad4 = *(const float4*)(ald + (size_t)d * 4);
    float base[4] = {as4.x + ad4.x, as4.y + ad4.y, as4.z + ad4.z, as4.w + ad4.w};
    float o[4];
    #pragma unroll
    for (int h = 0; h < 4; ++h) {
        float ale = 0.f;
        #pragma unroll
        for (int j = 0; j < 8; ++j) ale += av[j] * weff[j * 4 + h];
        float v = base[h] + ale;
        v = (v >= 0.f) ? v : NEG_SLOPE * v;
        o[h] = v;
        atomicMaxFloat(&m[(size_t)d * 4 + h], v);
    }
    *(float4*)(alpha + (size_t)e * 4) = make_float4(o[0], o[1], o[2], o[3]);
}

// ---- pass B: ex = exp(alpha - m[dst]); atomic segment sum into den; alpha := ex ----
__global__ void attn_exp_kernel(const int* __restrict__ ei,
                                const float* __restrict__ m,
                                float* __restrict__ alpha, float* __restrict__ den) {
    int e = blockIdx.x * blockDim.x + threadIdx.x;
    if (e >= E_SL) return;
    int d = (e < N_EDGES) ? ei[N_EDGES + e] : (e - N_EDGES);
    float4 a = *(float4*)(alpha + (size_t)e * 4);
    float4 mv = *(const float4*)(m + (size_t)d * 4);
    float e0 = expf(a.x - mv.x);
    float e1 = expf(a.y - mv.y);
    float e2 = expf(a.z - mv.z);
    float e3 = expf(a.w - mv.w);
    *(float4*)(alpha + (size_t)e * 4) = make_float4(e0, e1, e2, e3);
    atomicAdd(&den[(size_t)d * 4 + 0], e0);
    atomicAdd(&den[(size_t)d * 4 + 1], e1);
    atomicAdd(&den[(size_t)d * 4 + 2], e2);
    atomicAdd(&den[(size_t)d * 4 + 3], e3);
}

// ---- pass C: out[dst] += xp[src] * ex/(den[dst]+eps). One wave per edge. ----
__global__ void aggregate_kernel(const int* __restrict__ ei,
                                 const float* __restrict__ xp, const float* __restrict__ alpha,
                                 const float* __restrict__ den, float* __restrict__ out) {
    int e = blockIdx.x * 4 + (threadIdx.x >> 6);
    if (e >= E_SL) return;
    int lane = threadIdx.x & 63;
    int s, d;
    if (e < N_EDGES) { s = ei[e]; d = ei[N_EDGES + e]; }
    else             { s = e - N_EDGES; d = s; }
    int h = lane >> 4;
    float ex = alpha[(size_t)e * 4 + h];
    float dn = den[(size_t)d * 4 + h];
    float coef = ex / (dn + 1e-16f);
    float v = xp[(size_t)s * 64 + lane] * coef;
    atomicAdd(&out[(size_t)d * 64 + lane], v);
}

__global__ void bias_act_kernel(float* __restrict__ h, const float* __restrict__ b, int do_relu) {
    int i = blockIdx.x * blockDim.x + threadIdx.x;
    if (i >= N_NODES * 64) return;
    float v = h[i] + b[i & 63];
    if (do_relu) v = fmaxf(v, 0.f);
    h[i] = v;
}

// ---- graph mean pool: one block per graph; batch is sorted -> binary-search bounds ----
__global__ void pool_kernel(const float* __restrict__ h, const int* __restrict__ batch,
                            float* __restrict__ pooled) {
    int g = blockIdx.x;
    int lo = 0, hi = N_NODES;
    while (lo < hi) { int mid = (lo + hi) >> 1; if (batch[mid] < g) lo = mid + 1; else hi = mid; }
    int start = lo;
    hi = N_NODES;
    while (lo < hi) { int mid = (lo + hi) >> 1; if (batch[mid] < g + 1) lo = mid + 1; else hi = mid; }
    int end = lo;
    int tid = threadIdx.x;
    int c = tid & 63, r = tid >> 6;
    float acc = 0.f;
    for (int n = start + r; n < end; n += 4) acc += h[(size_t)n * 64 + c];
    __shared__ float red[256];
    red[tid] = acc;
    __syncthreads();
    if (tid < 64) {
        float s = red[tid] + red[tid + 64] + red[tid + 128] + red[tid + 192];
        float cg = fmaxf((float)(end - start), 1.0f);
        pooled[g * 64 + tid] = s / cg;
    }
}

// ---- MLP head: relu(p @ fc1 + b1) @ fc2 + b2 ----
__global__ void mlp_kernel(const float* __restrict__ pooled,
                           const float* __restrict__ w1, const float* __restrict__ b1,
                           const float* __restrict__ w2, const float* __restrict__ b2,
                           float* __restrict__ y) {
    int g = blockIdx.x, t = threadIdx.x;
    __shared__ float p[64], f1[32];
    p[t] = pooled[g * 64 + t];
    __syncthreads();
    if (t < 32) {
        float a = b1[t];
        #pragma unroll
        for (int k = 0; k < 64; ++k) a += p[k] * w1[k * 32 + t];
        f1[t] = fmaxf(a, 0.f);
    }
    __syncthreads();
    if (t < 2) {
        float a = b2[t];
        #pragma unroll
        for (int k = 0; k < 32; ++k) a += f1[k] * w2[k * 2 + t];
        y[g * 2 + t] = a;
    }
}

extern "C" void kernel_launch(void* const* d_in, const int* in_sizes, int n_in,
                              void* d_out, int out_size, void* d_ws, size_t ws_size,
                              hipStream_t stream) {
    const float* x    = (const float*)d_in[0];
    const int*   ei   = (const int*)d_in[1];
    const float* ea   = (const float*)d_in[2];
    const int*   batch= (const int*)d_in[3];
    const float* W0   = (const float*)d_in[4];
    const float* as0  = (const float*)d_in[5];
    const float* ad0  = (const float*)d_in[6];
    const float* We0  = (const float*)d_in[7];
    const float* ae0  = (const float*)d_in[8];
    const float* b0   = (const float*)d_in[9];
    const float* Wh   = (const float*)d_in[10];
    const float* ash  = (const float*)d_in[11];
    const float* adh  = (const float*)d_in[12];
    const float* Weh  = (const float*)d_in[13];
    const float* aeh  = (const float*)d_in[14];
    const float* bh   = (const float*)d_in[15];
    const float* w1   = (const float*)d_in[16];
    const float* b1   = (const float*)d_in[17];
    const float* w2   = (const float*)d_in[18];
    const float* b2   = (const float*)d_in[19];
    float* out = (float*)d_out;

    float* ws = (float*)d_ws;
    size_t off = 0;
    float* cnt    = ws + off; off += N_NODES;
    float* mattr  = ws + off; off += (size_t)N_NODES * 8;
    float* xp     = ws + off; off += (size_t)N_NODES * 64;
    float* als    = ws + off; off += (size_t)N_NODES * 4;
    float* ald    = ws + off; off += (size_t)N_NODES * 4;
    float* m      = ws + off; off += (size_t)N_NODES * 4;
    float* den    = ws + off; off += (size_t)N_NODES * 4;
    float* alpha  = ws + off; off += (size_t)E_SL * 4;
    float* ha     = ws + off; off += (size_t)N_NODES * 64;
    float* hb     = ws + off; off += (size_t)N_NODES * 64;
    float* weff   = ws + off; off += 32;
    float* pooled = ws + off; off += NUM_GRAPHS * 64;

    // self-loop mean edge attr (shared by all 3 layers)
    hipMemsetAsync(cnt, 0, N_NODES * sizeof(float), stream);
    hipMemsetAsync(mattr, 0, (size_t)N_NODES * 8 * sizeof(float), stream);
    deg_sum_kernel<<<(int)(((long long)N_EDGES * 8 + 255) / 256), 256, 0, stream>>>(ei, ea, cnt, mattr);
    mean_fin_kernel<<<(N_NODES * 8 + 255) / 256, 256, 0, stream>>>(cnt, mattr);

    for (int layer = 0; layer < 3; ++layer) {
        const float *W, *as_, *ad_, *We, *ae_, *bb, *xin;
        float* hout;
        int relu_flag = (layer == 0);
        if (layer == 0) {
            W = W0; as_ = as0; ad_ = ad0; We = We0; ae_ = ae0; bb = b0;
            xin = x; hout = ha;
        } else {
            int i = layer - 1;
            W   = Wh  + (size_t)i * 64 * 64;
            as_ = ash + (size_t)i * 64;
            ad_ = adh + (size_t)i * 64;
            We  = Weh + (size_t)i * 8 * 64;
            ae_ = aeh + (size_t)i * 64;
            bb  = bh  + (size_t)i * 64;
            xin  = (layer == 1) ? ha : hb;
            hout = (layer == 1) ? hb : ha;
        }
        weff_kernel<<<1, 32, 0, stream>>>(We, ae_, weff);
        if (layer == 0)
            xp_kernel<32><<<(N_NODES + 3) / 4, 256, 0, stream>>>(xin, W, as_, ad_, xp, als, ald);
        else
            xp_kernel<64><<<(N_NODES + 3) / 4, 256, 0, stream>>>(xin, W, as_, ad_, xp, als, ald);
        hipMemsetAsync(m, 0xFF, (size_t)N_NODES * 4 * sizeof(float), stream);   // -max sentinel
        hipMemsetAsync(den, 0, (size_t)N_NODES * 4 * sizeof(float), stream);
        attn_logit_kernel<<<(E_SL + 255) / 256, 256, 0, stream>>>(ei, ea, mattr, als, ald, weff, alpha, m);
        attn_exp_kernel<<<(E_SL + 255) / 256, 256, 0, stream>>>(ei, m, alpha, den);
        hipMemsetAsync(hout, 0, (size_t)N_NODES * 64 * sizeof(float), stream);
        aggregate_kernel<<<(E_SL + 3) / 4, 256, 0, stream>>>(ei, xp, alpha, den, hout);
        bias_act_kernel<<<(N_NODES * 64 + 255) / 256, 256, 0, stream>>>(hout, bb, relu_flag);
    }
    pool_kernel<<<NUM_GRAPHS, 256, 0, stream>>>(ha, batch, pooled);
    mlp_kernel<<<NUM_GRAPHS, 64, 0, stream>>>(pooled, w1, b1, w2, b2, out);
}

// Round 3
// 1240.288 us; speedup vs baseline: 2.7946x; 2.7946x over previous
//
#include <hip/hip_runtime.h>
#include <hip/hip_bf16.h>

#define N_NODES 100000
#define N_EDGES 1600000
#define E_SL (N_EDGES + N_NODES)
#define HID 64
#define NUM_GRAPHS 64
#define NEG_SLOPE 0.2f
#define SCAN_CHUNK 1024
#define SCAN_NB ((N_NODES + SCAN_CHUNK - 1) / SCAN_CHUNK)

// ============ CSR build (once per call, reused by all 3 layers) ============

__global__ void hist_kernel(const int* __restrict__ ei, int* __restrict__ cnt) {
    int e = blockIdx.x * blockDim.x + threadIdx.x;
    if (e >= N_EDGES) return;
    atomicAdd(&cnt[ei[N_EDGES + e]], 1);
}

// exclusive scan of (cnt[i]+1): block-local pass
__global__ void scan_local_kernel(const int* __restrict__ cnt, int* __restrict__ row_ptr,
                                  int* __restrict__ bsum) {
    __shared__ int s[256];
    int t = threadIdx.x;
    int base = blockIdx.x * SCAN_CHUNK + t * 4;
    int v[4]; int sum = 0;
    #pragma unroll
    for (int i = 0; i < 4; ++i) {
        int idx = base + i;
        v[i] = (idx < N_NODES) ? cnt[idx] + 1 : 0;
        sum += v[i];
    }
    s[t] = sum;
    __syncthreads();
    for (int off = 1; off < 256; off <<= 1) {
        int x = (t >= off) ? s[t - off] : 0;
        __syncthreads();
        s[t] += x;
        __syncthreads();
    }
    int run = s[t] - sum;  // exclusive prefix of this thread within block
    #pragma unroll
    for (int i = 0; i < 4; ++i) {
        int idx = base + i;
        if (idx < N_NODES) row_ptr[idx] = run;
        run += v[i];
    }
    if (t == 255) bsum[blockIdx.x] = s[255];
}

__global__ void scan_bsum_kernel(int* __restrict__ bsum) {
    if (threadIdx.x != 0) return;
    int acc = 0;
    for (int i = 0; i < SCAN_NB; ++i) { int v = bsum[i]; bsum[i] = acc; acc += v; }
}

__global__ void scan_add_kernel(int* __restrict__ row_ptr, const int* __restrict__ bsum) {
    int i = blockIdx.x * blockDim.x + threadIdx.x;
    if (i > N_NODES) return;
    if (i == N_NODES) row_ptr[i] = E_SL;
    else row_ptr[i] += bsum[i >> 10];
}

__global__ void scatter_kernel(const int* __restrict__ ei, const int* __restrict__ row_ptr,
                               int* __restrict__ cursor, int* __restrict__ col,
                               int* __restrict__ eid) {
    int e = blockIdx.x * blockDim.x + threadIdx.x;
    if (e >= N_EDGES) return;
    int d = ei[N_EDGES + e];
    int pos = row_ptr[d] + atomicAdd(&cursor[d], 1);
    col[pos] = ei[e];
    eid[pos] = e;
}

// self-loop slot (last in each segment) + mean edge attr for it. idx = node*8+j
__global__ void selfloop_kernel(const int* __restrict__ row_ptr, int* __restrict__ col,
                                int* __restrict__ eid, const float* __restrict__ ea,
                                float* __restrict__ mattr) {
    int idx = blockIdx.x * blockDim.x + threadIdx.x;
    if (idx >= N_NODES * 8) return;
    int n = idx >> 3, j = idx & 7;
    int start = row_ptr[n], last = row_ptr[n + 1] - 1;
    float s = 0.f;
    for (int pos = start; pos < last; ++pos) s += ea[(size_t)eid[pos] * 8 + j];
    int degr = last - start;
    mattr[(size_t)n * 8 + j] = s / fmaxf((float)degr, 1.f);
    if (j == 0) { col[last] = n; eid[last] = N_EDGES + n; }
}

// ============ per-layer kernels ============

// fold We (8x64) and att_e (4x16) into weff[8][4]
__global__ void weff_kernel(const float* __restrict__ We, const float* __restrict__ ae,
                            float* __restrict__ weff) {
    int t = threadIdx.x;
    if (t >= 32) return;
    int dd = t >> 2, h = t & 3;
    float s = 0.f;
    #pragma unroll
    for (int c = 0; c < 16; ++c) s += We[dd * 64 + h * 16 + c] * ae[h * 16 + c];
    weff[dd * 4 + h] = s;
}

// xp = x @ W ; als/ald per-node logits. One wave per node (64 cols).
template <int FIN>
__global__ void xp_kernel(const float* __restrict__ xin, const float* __restrict__ W,
                          const float* __restrict__ a_s, const float* __restrict__ a_d,
                          float* __restrict__ xp, float* __restrict__ als, float* __restrict__ ald) {
    __shared__ float Wl[FIN * 64];
    __shared__ float xr[4 * FIN];
    int tid = threadIdx.x;
    for (int i = tid; i < FIN * 64; i += 256) Wl[i] = W[i];
    int n0 = blockIdx.x * 4;
    for (int i = tid; i < 4 * FIN; i += 256) {
        int r = i / FIN, k = i - r * FIN;
        int n = n0 + r;
        xr[i] = (n < N_NODES) ? xin[(size_t)n * FIN + k] : 0.f;
    }
    __syncthreads();
    int w = tid >> 6, lane = tid & 63;
    int n = n0 + w;
    if (n >= N_NODES) return;
    float acc = 0.f;
    const float* xrow = xr + w * FIN;
    #pragma unroll
    for (int k = 0; k < FIN; ++k) acc += xrow[k] * Wl[k * 64 + lane];
    xp[(size_t)n * 64 + lane] = acc;
    float ps = acc * a_s[lane];
    float pd = acc * a_d[lane];
    #pragma unroll
    for (int mk = 8; mk >= 1; mk >>= 1) {
        ps += __shfl_xor(ps, mk, 16);
        pd += __shfl_xor(pd, mk, 16);
    }
    if ((lane & 15) == 0) {
        als[(size_t)n * 4 + (lane >> 4)] = ps;
        ald[(size_t)n * 4 + (lane >> 4)] = pd;
    }
}

// Fused GAT: one wave per node. Phase1 logits+max, Phase2 exp+sum, Phase3 aggregate.
// No atomics; out written once, coalesced. threadfence_block between phases:
// phase3 reads alphab entries written by OTHER lanes (VMEM returns are unordered).
__global__ __launch_bounds__(256) void gat_node_kernel(
    const int* __restrict__ row_ptr, const int* __restrict__ col, const int* __restrict__ eid,
    const float* __restrict__ ea, const float* __restrict__ mattr,
    const float* __restrict__ als, const float* __restrict__ ald,
    const float* __restrict__ weff, const float* __restrict__ xp,
    float* __restrict__ alphab, float* __restrict__ out,
    const float* __restrict__ bias, int relu_flag) {
    int node = blockIdx.x * 4 + (threadIdx.x >> 6);
    if (node >= N_NODES) return;
    int lane = threadIdx.x & 63;
    int start = row_ptr[node], end = row_ptr[node + 1];
    int deg = end - start;                    // >= 1 (self-loop)
    int h4 = lane & 3;                        // head for phases 1-2

    float wcol[8];
    #pragma unroll
    for (int j = 0; j < 8; ++j) wcol[j] = weff[j * 4 + h4];
    float aldh = ald[(size_t)node * 4 + h4];

    // ---- phase 1: logits + per-head max (lane = local_edge*4 + head) ----
    float m = -1e30f;
    for (int base = 0; base < deg; base += 16) {
        int le = base + (lane >> 2);
        float logit = -1e30f;
        if (le < deg) {
            int pos = start + le;
            int s = col[pos];
            int e = eid[pos];
            const float* ap = (e < N_EDGES) ? ea + (size_t)e * 8
                                            : mattr + (size_t)(e - N_EDGES) * 8;
            float4 a0 = *(const float4*)ap;
            float4 a1 = *(const float4*)(ap + 4);
            float ale = a0.x * wcol[0] + a0.y * wcol[1] + a0.z * wcol[2] + a0.w * wcol[3]
                      + a1.x * wcol[4] + a1.y * wcol[5] + a1.z * wcol[6] + a1.w * wcol[7];
            float v = als[(size_t)s * 4 + h4] + aldh + ale;
            v = (v >= 0.f) ? v : NEG_SLOPE * v;
            alphab[(size_t)pos * 4 + h4] = v;
            logit = v;
        }
        m = fmaxf(m, logit);
    }
    #pragma unroll
    for (int mk = 4; mk < 64; mk <<= 1) m = fmaxf(m, __shfl_xor(m, mk));
    __threadfence_block();

    // ---- phase 2: exp + per-head denom ----
    float den = 0.f;
    for (int base = 0; base < deg; base += 16) {
        int le = base + (lane >> 2);
        if (le < deg) {
            size_t idx = (size_t)(start + le) * 4 + h4;
            float ex = expf(alphab[idx] - m);
            alphab[idx] = ex;
            den += ex;
        }
    }
    #pragma unroll
    for (int mk = 4; mk < 64; mk <<= 1) den += __shfl_xor(den, mk);
    float inv = 1.f / (den + 1e-16f);
    float invh = __shfl(inv, lane >> 4);      // inv for head (lane>>4): lane k<4 has h=k
    __threadfence_block();

    // ---- phase 3: aggregate (lane = output column, head = lane>>4) ----
    int hq = lane >> 4;
    float acc = 0.f;
    for (int pos = start; pos < end; ++pos) {
        int s = col[pos];
        float ex = alphab[(size_t)pos * 4 + hq];
        acc += xp[(size_t)s * 64 + lane] * ex;
    }
    float v = acc * invh + bias[lane];
    if (relu_flag) v = fmaxf(v, 0.f);
    out[(size_t)node * 64 + lane] = v;
}

// ---- graph mean pool: one block per graph; batch sorted -> binary-search bounds ----
__global__ void pool_kernel(const float* __restrict__ h, const int* __restrict__ batch,
                            float* __restrict__ pooled) {
    int g = blockIdx.x;
    int lo = 0, hi = N_NODES;
    while (lo < hi) { int mid = (lo + hi) >> 1; if (batch[mid] < g) lo = mid + 1; else hi = mid; }
    int start = lo;
    hi = N_NODES;
    while (lo < hi) { int mid = (lo + hi) >> 1; if (batch[mid] < g + 1) lo = mid + 1; else hi = mid; }
    int end = lo;
    int tid = threadIdx.x;
    int c = tid & 63, r = tid >> 6;
    float acc = 0.f;
    for (int n = start + r; n < end; n += 4) acc += h[(size_t)n * 64 + c];
    __shared__ float red[256];
    red[tid] = acc;
    __syncthreads();
    if (tid < 64) {
        float s = red[tid] + red[tid + 64] + red[tid + 128] + red[tid + 192];
        float cg = fmaxf((float)(end - start), 1.0f);
        pooled[g * 64 + tid] = s / cg;
    }
}

__global__ void mlp_kernel(const float* __restrict__ pooled,
                           const float* __restrict__ w1, const float* __restrict__ b1,
                           const float* __restrict__ w2, const float* __restrict__ b2,
                           float* __restrict__ y) {
    int g = blockIdx.x, t = threadIdx.x;
    __shared__ float p[64], f1[32];
    p[t] = pooled[g * 64 + t];
    __syncthreads();
    if (t < 32) {
        float a = b1[t];
        #pragma unroll
        for (int k = 0; k < 64; ++k) a += p[k] * w1[k * 32 + t];
        f1[t] = fmaxf(a, 0.f);
    }
    __syncthreads();
    if (t < 2) {
        float a = b2[t];
        #pragma unroll
        for (int k = 0; k < 32; ++k) a += f1[k] * w2[k * 2 + t];
        y[g * 2 + t] = a;
    }
}

extern "C" void kernel_launch(void* const* d_in, const int* in_sizes, int n_in,
                              void* d_out, int out_size, void* d_ws, size_t ws_size,
                              hipStream_t stream) {
    const float* x    = (const float*)d_in[0];
    const int*   ei   = (const int*)d_in[1];
    const float* ea   = (const float*)d_in[2];
    const int*   batch= (const int*)d_in[3];
    const float* W0   = (const float*)d_in[4];
    const float* as0  = (const float*)d_in[5];
    const float* ad0  = (const float*)d_in[6];
    const float* We0  = (const float*)d_in[7];
    const float* ae0  = (const float*)d_in[8];
    const float* b0   = (const float*)d_in[9];
    const float* Wh   = (const float*)d_in[10];
    const float* ash  = (const float*)d_in[11];
    const float* adh  = (const float*)d_in[12];
    const float* Weh  = (const float*)d_in[13];
    const float* aeh  = (const float*)d_in[14];
    const float* bh   = (const float*)d_in[15];
    const float* w1   = (const float*)d_in[16];
    const float* b1   = (const float*)d_in[17];
    const float* w2   = (const float*)d_in[18];
    const float* b2   = (const float*)d_in[19];
    float* out = (float*)d_out;

    char* wsb = (char*)d_ws;
    size_t off = 0;
    auto alloc = [&](size_t bytes) { char* p = wsb + off; off += (bytes + 255) & ~(size_t)255; return p; };
    int*   cnt     = (int*)alloc((size_t)N_NODES * 4);
    int*   row_ptr = (int*)alloc((size_t)(N_NODES + 1) * 4);
    int*   cursor  = (int*)alloc((size_t)N_NODES * 4);
    int*   bsum    = (int*)alloc((size_t)SCAN_NB * 4);
    int*   col     = (int*)alloc((size_t)E_SL * 4);
    int*   eid     = (int*)alloc((size_t)E_SL * 4);
    float* mattr   = (float*)alloc((size_t)N_NODES * 8 * 4);
    float* bufA    = (float*)alloc((size_t)N_NODES * 64 * 4);  // always xp
    float* bufB    = (float*)alloc((size_t)N_NODES * 64 * 4);  // always h (layer output)
    float* als     = (float*)alloc((size_t)N_NODES * 4 * 4);
    float* ald     = (float*)alloc((size_t)N_NODES * 4 * 4);
    float* alphab  = (float*)alloc((size_t)E_SL * 4 * 4);
    float* weff    = (float*)alloc(32 * 4);
    float* pooled  = (float*)alloc((size_t)NUM_GRAPHS * 64 * 4);

    // ---- CSR build (once) ----
    hipMemsetAsync(cnt, 0, (size_t)N_NODES * 4, stream);
    hipMemsetAsync(cursor, 0, (size_t)N_NODES * 4, stream);
    hist_kernel<<<(N_EDGES + 255) / 256, 256, 0, stream>>>(ei, cnt);
    scan_local_kernel<<<SCAN_NB, 256, 0, stream>>>(cnt, row_ptr, bsum);
    scan_bsum_kernel<<<1, 64, 0, stream>>>(bsum);
    scan_add_kernel<<<(N_NODES + 256) / 256, 256, 0, stream>>>(row_ptr, bsum);
    scatter_kernel<<<(N_EDGES + 255) / 256, 256, 0, stream>>>(ei, row_ptr, cursor, col, eid);
    selfloop_kernel<<<(N_NODES * 8 + 255) / 256, 256, 0, stream>>>(row_ptr, col, eid, ea, mattr);

    // ---- 3 GAT layers (buffer plan: xin -> bufA(xp) -> bufB(h); bufB feeds next layer) ----
    for (int layer = 0; layer < 3; ++layer) {
        const float *W, *as_, *ad_, *We, *ae_, *bb, *xin;
        int relu_flag = (layer == 0);
        if (layer == 0) {
            W = W0; as_ = as0; ad_ = ad0; We = We0; ae_ = ae0; bb = b0;
            xin = x;
        } else {
            int i = layer - 1;
            W   = Wh  + (size_t)i * 64 * 64;
            as_ = ash + (size_t)i * 64;
            ad_ = adh + (size_t)i * 64;
            We  = Weh + (size_t)i * 8 * 64;
            ae_ = aeh + (size_t)i * 64;
            bb  = bh  + (size_t)i * 64;
            xin = bufB;   // previous layer output; consumed by xp_kernel only
        }
        weff_kernel<<<1, 32, 0, stream>>>(We, ae_, weff);
        if (layer == 0)
            xp_kernel<32><<<(N_NODES + 3) / 4, 256, 0, stream>>>(xin, W, as_, ad_, bufA, als, ald);
        else
            xp_kernel<64><<<(N_NODES + 3) / 4, 256, 0, stream>>>(xin, W, as_, ad_, bufA, als, ald);
        gat_node_kernel<<<(N_NODES + 3) / 4, 256, 0, stream>>>(
            row_ptr, col, eid, ea, mattr, als, ald, weff, bufA, alphab, bufB, bb, relu_flag);
    }
    pool_kernel<<<NUM_GRAPHS, 256, 0, stream>>>(bufB, batch, pooled);
    mlp_kernel<<<NUM_GRAPHS, 64, 0, stream>>>(pooled, w1, b1, w2, b2, out);
}

// Round 5
// 885.980 us; speedup vs baseline: 3.9121x; 1.3999x over previous
//
#include <hip/hip_runtime.h>
#include <hip/hip_bf16.h>

#define N_NODES 100000
#define N_EDGES 1600000
#define E_SL (N_EDGES + N_NODES)
#define HID 64
#define NUM_GRAPHS 64
#define NEG_SLOPE 0.2f
#define SCAN_CHUNK 1024
#define SCAN_NB ((N_NODES + SCAN_CHUNK - 1) / SCAN_CHUNK)

// ============ CSR build (once per call, reused by all 3 layers) ============

__global__ void hist_kernel(const int* __restrict__ ei, int* __restrict__ cnt) {
    int e = blockIdx.x * blockDim.x + threadIdx.x;
    if (e >= N_EDGES) return;
    atomicAdd(&cnt[ei[N_EDGES + e]], 1);
}

// exclusive scan of (cnt[i]+1): block-local pass
__global__ void scan_local_kernel(const int* __restrict__ cnt, int* __restrict__ row_ptr,
                                  int* __restrict__ bsum) {
    __shared__ int s[256];
    int t = threadIdx.x;
    int base = blockIdx.x * SCAN_CHUNK + t * 4;
    int v[4]; int sum = 0;
    #pragma unroll
    for (int i = 0; i < 4; ++i) {
        int idx = base + i;
        v[i] = (idx < N_NODES) ? cnt[idx] + 1 : 0;
        sum += v[i];
    }
    s[t] = sum;
    __syncthreads();
    for (int off = 1; off < 256; off <<= 1) {
        int x = (t >= off) ? s[t - off] : 0;
        __syncthreads();
        s[t] += x;
        __syncthreads();
    }
    int run = s[t] - sum;
    #pragma unroll
    for (int i = 0; i < 4; ++i) {
        int idx = base + i;
        if (idx < N_NODES) row_ptr[idx] = run;
        run += v[i];
    }
    if (t == 255) bsum[blockIdx.x] = s[255];
}

__global__ void scan_bsum_kernel(int* __restrict__ bsum) {
    if (threadIdx.x != 0) return;
    int acc = 0;
    for (int i = 0; i < SCAN_NB; ++i) { int v = bsum[i]; bsum[i] = acc; acc += v; }
}

__global__ void scan_add_kernel(int* __restrict__ row_ptr, const int* __restrict__ bsum) {
    int i = blockIdx.x * blockDim.x + threadIdx.x;
    if (i > N_NODES) return;
    if (i == N_NODES) row_ptr[i] = E_SL;
    else row_ptr[i] += bsum[i >> 10];
}

__global__ void scatter_kernel(const int* __restrict__ ei, const int* __restrict__ row_ptr,
                               int* __restrict__ cursor, int* __restrict__ col,
                               int* __restrict__ eid) {
    int e = blockIdx.x * blockDim.x + threadIdx.x;
    if (e >= N_EDGES) return;
    int d = ei[N_EDGES + e];
    int pos = row_ptr[d] + atomicAdd(&cursor[d], 1);
    col[pos] = ei[e];
    eid[pos] = e;
}

// mark self-loop slot (last in each segment)
__global__ void mark_selfloop_kernel(const int* __restrict__ row_ptr, int* __restrict__ col,
                                     int* __restrict__ eid) {
    int n = blockIdx.x * blockDim.x + threadIdx.x;
    if (n >= N_NODES) return;
    int last = row_ptr[n + 1] - 1;
    col[last] = n;
    eid[last] = -1;
}

// ea_csr[pos*8+j] = ea[eid[pos]*8+j]  (random 32B reads, coalesced writes). Once per call.
__global__ void permute_ea_kernel(const int* __restrict__ eid, const float* __restrict__ ea,
                                  float* __restrict__ ea_csr) {
    long long idx = (long long)blockIdx.x * blockDim.x + threadIdx.x;
    if (idx >= (long long)E_SL * 8) return;
    int pos = (int)(idx >> 3), j = (int)(idx & 7);
    int e = eid[pos];
    ea_csr[idx] = (e >= 0) ? ea[(size_t)e * 8 + j] : 0.f;
}

// self-loop attr = mean of real incoming attrs: contiguous (coalesced) segment sum over ea_csr
__global__ void mean_ea_kernel(const int* __restrict__ row_ptr, float* __restrict__ ea_csr) {
    int idx = blockIdx.x * blockDim.x + threadIdx.x;
    if (idx >= N_NODES * 8) return;
    int n = idx >> 3, j = idx & 7;
    int start = row_ptr[n], last = row_ptr[n + 1] - 1;
    float s = 0.f;
    for (int pos = start; pos < last; ++pos) s += ea_csr[(size_t)pos * 8 + j];
    ea_csr[(size_t)last * 8 + j] = s / fmaxf((float)(last - start), 1.f);
}

// ============ per-layer kernels ============

// fold We (8x64) + att_e (4x16) into weff[layer][8][4] for all 3 layers at once
__global__ void weff_all_kernel(const float* __restrict__ We0, const float* __restrict__ ae0,
                                const float* __restrict__ Weh, const float* __restrict__ aeh,
                                float* __restrict__ weff) {
    int t = threadIdx.x;
    if (t >= 96) return;
    int layer = t >> 5, r = t & 31;
    int dd = r >> 2, h = r & 3;
    const float* We = (layer == 0) ? We0 : Weh + (size_t)(layer - 1) * 8 * 64;
    const float* ae = (layer == 0) ? ae0 : aeh + (size_t)(layer - 1) * 64;
    float s = 0.f;
    #pragma unroll
    for (int c = 0; c < 16; ++c) s += We[dd * 64 + h * 16 + c] * ae[h * 16 + c];
    weff[layer * 32 + dd * 4 + h] = s;
}

// xp = x @ W ; als/ald per-node logits. One wave per node (64 cols).
template <int FIN>
__global__ void xp_kernel(const float* __restrict__ xin, const float* __restrict__ W,
                          const float* __restrict__ a_s, const float* __restrict__ a_d,
                          float* __restrict__ xp, float* __restrict__ als, float* __restrict__ ald) {
    __shared__ float Wl[FIN * 64];
    __shared__ float xr[4 * FIN];
    int tid = threadIdx.x;
    for (int i = tid; i < FIN * 64; i += 256) Wl[i] = W[i];
    int n0 = blockIdx.x * 4;
    for (int i = tid; i < 4 * FIN; i += 256) {
        int r = i / FIN, k = i - r * FIN;
        int n = n0 + r;
        xr[i] = (n < N_NODES) ? xin[(size_t)n * FIN + k] : 0.f;
    }
    __syncthreads();
    int w = tid >> 6, lane = tid & 63;
    int n = n0 + w;
    if (n >= N_NODES) return;
    float acc = 0.f;
    const float* xrow = xr + w * FIN;
    #pragma unroll
    for (int k = 0; k < FIN; ++k) acc += xrow[k] * Wl[k * 64 + lane];
    xp[(size_t)n * 64 + lane] = acc;
    float ps = acc * a_s[lane];
    float pd = acc * a_d[lane];
    #pragma unroll
    for (int mk = 8; mk >= 1; mk >>= 1) {
        ps += __shfl_xor(ps, mk, 16);
        pd += __shfl_xor(pd, mk, 16);
    }
    if ((lane & 15) == 0) {
        als[(size_t)n * 4 + (lane >> 4)] = ps;
        ald[(size_t)n * 4 + (lane >> 4)] = pd;
    }
}

__device__ __forceinline__ float pick4(float a, float b, float c, float d, int h) {
    float ab = (h & 1) ? b : a;
    float cd = (h & 1) ? d : c;
    return (h & 2) ? cd : ab;
}

// Fused GAT with ONLINE softmax: one wave per node, lane = edge within 64-wide chunk.
// Single pass over edges; coefficients staged per-wave in LDS (wave-private regions,
// wave-synchronous access -> no __syncthreads needed); no alphab buffer, no atomics.
__global__ __launch_bounds__(256) void gat_node_kernel(
    const int* __restrict__ row_ptr, const int* __restrict__ col,
    const float* __restrict__ ea_csr,
    const float* __restrict__ als, const float* __restrict__ ald,
    const float* __restrict__ weff, const float* __restrict__ xp,
    float* __restrict__ out, const float* __restrict__ bias, int relu_flag) {
    __shared__ float exl[4 * 256];   // per-wave: 64 edges x 4 heads
    __shared__ int   coll[4 * 64];   // per-wave: 64 src ids
    int wave = threadIdx.x >> 6, lane = threadIdx.x & 63;
    int node = blockIdx.x * 4 + wave;
    if (node >= N_NODES) return;
    int start = row_ptr[node], end = row_ptr[node + 1];
    int deg = end - start;                       // >= 1 (self-loop)
    int hq = lane >> 4;                          // head for aggregation (lane = out col)
    int wb = wave * 64, wb4 = wave * 256;

    // weff rows as float4 (8 x 4 heads), dst logit per head
    float4 w0 = *(const float4*)(weff + 0),  w1 = *(const float4*)(weff + 4);
    float4 w2 = *(const float4*)(weff + 8),  w3 = *(const float4*)(weff + 12);
    float4 w4 = *(const float4*)(weff + 16), w5 = *(const float4*)(weff + 20);
    float4 w6 = *(const float4*)(weff + 24), w7 = *(const float4*)(weff + 28);
    float4 ad4 = *(const float4*)(ald + (size_t)node * 4);

    float m[4] = {-1e30f, -1e30f, -1e30f, -1e30f};
    float den[4] = {0.f, 0.f, 0.f, 0.f};
    float acc = 0.f;

    for (int base = 0; base < deg; base += 64) {
        int cnt = min(64, deg - base);
        float lg[4] = {-1e30f, -1e30f, -1e30f, -1e30f};
        int s = 0;
        if (lane < cnt) {
            int pos = start + base + lane;
            s = col[pos];
            float4 a0 = *(const float4*)(ea_csr + (size_t)pos * 8);
            float4 a1 = *(const float4*)(ea_csr + (size_t)pos * 8 + 4);
            float4 as4 = *(const float4*)(als + (size_t)s * 4);
            #pragma unroll
            for (int h = 0; h < 4; ++h) {
                float ale = a0.x * pick4(w0.x, w0.y, w0.z, w0.w, h)
                          + a0.y * pick4(w1.x, w1.y, w1.z, w1.w, h)
                          + a0.z * pick4(w2.x, w2.y, w2.z, w2.w, h)
                          + a0.w * pick4(w3.x, w3.y, w3.z, w3.w, h)
                          + a1.x * pick4(w4.x, w4.y, w4.z, w4.w, h)
                          + a1.y * pick4(w5.x, w5.y, w5.z, w5.w, h)
                          + a1.z * pick4(w6.x, w6.y, w6.z, w6.w, h)
                          + a1.w * pick4(w7.x, w7.y, w7.z, w7.w, h);
                float v = pick4(as4.x, as4.y, as4.z, as4.w, h)
                        + pick4(ad4.x, ad4.y, ad4.z, ad4.w, h) + ale;
                lg[h] = (v >= 0.f) ? v : NEG_SLOPE * v;
            }
        }
        // chunk max per head -> running max + rescale
        float cm[4] = {lg[0], lg[1], lg[2], lg[3]};
        #pragma unroll
        for (int mk = 1; mk < 64; mk <<= 1) {
            #pragma unroll
            for (int h = 0; h < 4; ++h) cm[h] = fmaxf(cm[h], __shfl_xor(cm[h], mk));
        }
        float scale[4], ex[4];
        #pragma unroll
        for (int h = 0; h < 4; ++h) {
            float mn = fmaxf(m[h], cm[h]);
            scale[h] = expf(m[h] - mn);   // first chunk: exp(-inf)=0, benign
            m[h] = mn;
            ex[h] = (lane < cnt) ? expf(lg[h] - mn) : 0.f;
        }
        // stage coefficients + src ids in LDS (per-wave region)
        *(float4*)(exl + wb4 + lane * 4) = make_float4(ex[0], ex[1], ex[2], ex[3]);
        coll[wb + lane] = s;
        // chunk denominator
        float cd[4] = {ex[0], ex[1], ex[2], ex[3]};
        #pragma unroll
        for (int mk = 1; mk < 64; mk <<= 1) {
            #pragma unroll
            for (int h = 0; h < 4; ++h) cd[h] += __shfl_xor(cd[h], mk);
        }
        #pragma unroll
        for (int h = 0; h < 4; ++h) den[h] = den[h] * scale[h] + cd[h];
        // aggregate this chunk (lane = output column); unroll x4 for load overlap
        float acc2 = 0.f;
        int j = 0;
        for (; j + 4 <= cnt; j += 4) {
            int s0 = coll[wb + j + 0], s1 = coll[wb + j + 1];
            int s2 = coll[wb + j + 2], s3 = coll[wb + j + 3];
            float c0 = exl[wb4 + (j + 0) * 4 + hq], c1 = exl[wb4 + (j + 1) * 4 + hq];
            float c2 = exl[wb4 + (j + 2) * 4 + hq], c3 = exl[wb4 + (j + 3) * 4 + hq];
            float x0 = xp[(size_t)s0 * 64 + lane];
            float x1 = xp[(size_t)s1 * 64 + lane];
            float x2 = xp[(size_t)s2 * 64 + lane];
            float x3 = xp[(size_t)s3 * 64 + lane];
            acc2 += c0 * x0 + c1 * x1 + c2 * x2 + c3 * x3;
        }
        for (; j < cnt; ++j) {
            int sj = coll[wb + j];
            acc2 += exl[wb4 + j * 4 + hq] * xp[(size_t)sj * 64 + lane];
        }
        acc = acc * pick4(scale[0], scale[1], scale[2], scale[3], hq) + acc2;
    }
    float inv = 1.f / (pick4(den[0], den[1], den[2], den[3], hq) + 1e-16f);
    float v = acc * inv + bias[lane];
    if (relu_flag) v = fmaxf(v, 0.f);
    out[(size_t)node * 64 + lane] = v;
}

// ---- graph mean pool: one block per graph; batch sorted -> binary-search bounds ----
__global__ void pool_kernel(const float* __restrict__ h, const int* __restrict__ batch,
                            float* __restrict__ pooled) {
    int g = blockIdx.x;
    int lo = 0, hi = N_NODES;
    while (lo < hi) { int mid = (lo + hi) >> 1; if (batch[mid] < g) lo = mid + 1; else hi = mid; }
    int start = lo;
    hi = N_NODES;
    while (lo < hi) { int mid = (lo + hi) >> 1; if (batch[mid] < g + 1) lo = mid + 1; else hi = mid; }
    int end = lo;
    int tid = threadIdx.x;
    int c = tid & 63, r = tid >> 6;
    float acc = 0.f;
    for (int n = start + r; n < end; n += 4) acc += h[(size_t)n * 64 + c];
    __shared__ float red[256];
    red[tid] = acc;
    __syncthreads();
    if (tid < 64) {
        float s = red[tid] + red[tid + 64] + red[tid + 128] + red[tid + 192];
        float cg = fmaxf((float)(end - start), 1.0f);
        pooled[g * 64 + tid] = s / cg;
    }
}

__global__ void mlp_kernel(const float* __restrict__ pooled,
                           const float* __restrict__ w1, const float* __restrict__ b1,
                           const float* __restrict__ w2, const float* __restrict__ b2,
                           float* __restrict__ y) {
    int g = blockIdx.x, t = threadIdx.x;
    __shared__ float p[64], f1[32];
    p[t] = pooled[g * 64 + t];
    __syncthreads();
    if (t < 32) {
        float a = b1[t];
        #pragma unroll
        for (int k = 0; k < 64; ++k) a += p[k] * w1[k * 32 + t];
        f1[t] = fmaxf(a, 0.f);
    }
    __syncthreads();
    if (t < 2) {
        float a = b2[t];
        #pragma unroll
        for (int k = 0; k < 32; ++k) a += f1[k] * w2[k * 2 + t];
        y[g * 2 + t] = a;
    }
}

extern "C" void kernel_launch(void* const* d_in, const int* in_sizes, int n_in,
                              void* d_out, int out_size, void* d_ws, size_t ws_size,
                              hipStream_t stream) {
    const float* x    = (const float*)d_in[0];
    const int*   ei   = (const int*)d_in[1];
    const float* ea   = (const float*)d_in[2];
    const int*   batch= (const int*)d_in[3];
    const float* W0   = (const float*)d_in[4];
    const float* as0  = (const float*)d_in[5];
    const float* ad0  = (const float*)d_in[6];
    const float* We0  = (const float*)d_in[7];
    const float* ae0  = (const float*)d_in[8];
    const float* b0   = (const float*)d_in[9];
    const float* Wh   = (const float*)d_in[10];
    const float* ash  = (const float*)d_in[11];
    const float* adh  = (const float*)d_in[12];
    const float* Weh  = (const float*)d_in[13];
    const float* aeh  = (const float*)d_in[14];
    const float* bh   = (const float*)d_in[15];
    const float* w1   = (const float*)d_in[16];
    const float* b1   = (const float*)d_in[17];
    const float* w2   = (const float*)d_in[18];
    const float* b2   = (const float*)d_in[19];
    float* out = (float*)d_out;

    char* wsb = (char*)d_ws;
    size_t off = 0;
    auto alloc = [&](size_t bytes) { char* p = wsb + off; off += (bytes + 255) & ~(size_t)255; return p; };
    // persistent (~116 MB total)
    int*   row_ptr = (int*)alloc((size_t)(N_NODES + 1) * 4);
    int*   col     = (int*)alloc((size_t)E_SL * 4);
    float* ea_csr  = (float*)alloc((size_t)E_SL * 8 * 4);
    float* als     = (float*)alloc((size_t)N_NODES * 4 * 4);
    float* ald     = (float*)alloc((size_t)N_NODES * 4 * 4);
    float* weff    = (float*)alloc(3 * 32 * 4);
    float* pooled  = (float*)alloc((size_t)NUM_GRAPHS * 64 * 4);
    float* bufA    = (float*)alloc((size_t)N_NODES * 64 * 4);  // xp
    float* bufB    = (float*)alloc((size_t)N_NODES * 64 * 4);  // h (layer output)
    // CSR-build scratch ALIASED into bufA (all dead before xp_kernel writes bufA;
    // total 7.6 MB < 25.6 MB, same-stream ordering guarantees no overlap-in-time)
    int* cnt    = (int*)bufA;
    int* cursor = cnt + N_NODES;
    int* bsum   = cursor + N_NODES;
    int* eid    = bsum + ((SCAN_NB + 63) & ~63);

    // ---- CSR build + edge-attr permutation (once) ----
    hipMemsetAsync(cnt, 0, (size_t)N_NODES * 4, stream);
    hipMemsetAsync(cursor, 0, (size_t)N_NODES * 4, stream);
    hist_kernel<<<(N_EDGES + 255) / 256, 256, 0, stream>>>(ei, cnt);
    scan_local_kernel<<<SCAN_NB, 256, 0, stream>>>(cnt, row_ptr, bsum);
    scan_bsum_kernel<<<1, 64, 0, stream>>>(bsum);
    scan_add_kernel<<<(N_NODES + 256) / 256, 256, 0, stream>>>(row_ptr, bsum);
    scatter_kernel<<<(N_EDGES + 255) / 256, 256, 0, stream>>>(ei, row_ptr, cursor, col, eid);
    mark_selfloop_kernel<<<(N_NODES + 255) / 256, 256, 0, stream>>>(row_ptr, col, eid);
    permute_ea_kernel<<<(int)(((long long)E_SL * 8 + 255) / 256), 256, 0, stream>>>(eid, ea, ea_csr);
    mean_ea_kernel<<<(N_NODES * 8 + 255) / 256, 256, 0, stream>>>(row_ptr, ea_csr);
    weff_all_kernel<<<1, 128, 0, stream>>>(We0, ae0, Weh, aeh, weff);

    // ---- 3 GAT layers (xin -> bufA(xp) -> bufB(h); bufB feeds next layer) ----
    for (int layer = 0; layer < 3; ++layer) {
        const float *W, *as_, *ad_, *bb, *xin;
        int relu_flag = (layer == 0);
        if (layer == 0) {
            W = W0; as_ = as0; ad_ = ad0; bb = b0; xin = x;
        } else {
            int i = layer - 1;
            W   = Wh  + (size_t)i * 64 * 64;
            as_ = ash + (size_t)i * 64;
            ad_ = adh + (size_t)i * 64;
            bb  = bh  + (size_t)i * 64;
            xin = bufB;
        }
        if (layer == 0)
            xp_kernel<32><<<(N_NODES + 3) / 4, 256, 0, stream>>>(xin, W, as_, ad_, bufA, als, ald);
        else
            xp_kernel<64><<<(N_NODES + 3) / 4, 256, 0, stream>>>(xin, W, as_, ad_, bufA, als, ald);
        gat_node_kernel<<<(N_NODES + 3) / 4, 256, 0, stream>>>(
            row_ptr, col, ea_csr, als, ald, weff + layer * 32, bufA, bufB, bb, relu_flag);
    }
    pool_kernel<<<NUM_GRAPHS, 256, 0, stream>>>(bufB, batch, pooled);
    mlp_kernel<<<NUM_GRAPHS, 64, 0, stream>>>(pooled, w1, b1, w2, b2, out);
}